// Round 1
// baseline (502.519 us; speedup 1.0000x reference)
//
#include <hip/hip_runtime.h>
#include <math.h>

typedef __attribute__((ext_vector_type(4))) float f32x4;
typedef __attribute__((ext_vector_type(8))) short s16x8;
typedef __attribute__((ext_vector_type(8))) unsigned short u16x8;
typedef __attribute__((ext_vector_type(4))) unsigned short u16x4;

#define NB 32
#define NN 1000
#define NT 24
#define NP 1024
#define TCN 768

__device__ __forceinline__ unsigned short f2bf(float f){
  union { float fv; unsigned int u; } v; v.fv = f;
  unsigned int r = v.u + 0x7FFFu + ((v.u >> 16) & 1u);
  return (unsigned short)(r >> 16);
}

// ---------------- K0a: cheb[3][1000][1000] f32 -> cbT[3][1024][1024] bf16 (zero pad) ----
__global__ void k0_cheb(const float* __restrict__ cheb, unsigned short* __restrict__ cbT){
  int idx = blockIdx.x * 256 + threadIdx.x;      // 3*1024*1024/4 threads
  int base = idx << 2;
  int m = base & (NP - 1);
  int r = base >> 10;
  int n = r & (NP - 1);
  int k = r >> 10;
  u16x4 o;
  #pragma unroll
  for (int i = 0; i < 4; ++i){
    int mm = m + i;
    float v = (n < NN && mm < NN) ? cheb[((long)k*NN + n)*NN + mm] : 0.f;
    o[i] = f2bf(v);
  }
  *(u16x4*)(cbT + base) = o;
}

// ---------------- K0b: x[b][m][c][t] f32 -> xbT[b][t*32+c][1024 m] bf16 (pad m)
//                                        -> xt2[b][m][t*32+c] bf16 -----------------------
__global__ void k0_x(const float* __restrict__ x, unsigned short* __restrict__ xbT,
                     unsigned short* __restrict__ xt2){
  __shared__ unsigned short tile[16*768];
  int b  = blockIdx.x >> 6;
  int m0 = (blockIdx.x & 63) << 4;
  const float* xin = x + ((long)b*NN + m0) * 768;
  for (int i = threadIdx.x; i < 16*768; i += 256){
    int mi = i / 768, ct = i - mi*768;
    float v = (m0 + mi < NN) ? xin[(long)mi*768 + ct] : 0.f;
    tile[i] = f2bf(v);
  }
  __syncthreads();
  // xbT rows: tc = t*32+c, 16 m's per row
  unsigned short* ob = xbT + (long)b*TCN*NP + m0;
  for (int r = threadIdx.x; r < TCN; r += 256){
    int t = r >> 5, c = r & 31;
    int ct = c*24 + t;
    u16x8 lo, hi;
    #pragma unroll
    for (int mi = 0; mi < 8; ++mi) lo[mi] = tile[mi*768 + ct];
    #pragma unroll
    for (int mi = 0; mi < 8; ++mi) hi[mi] = tile[(mi+8)*768 + ct];
    *(u16x8*)(ob + (long)r*NP)     = lo;
    *(u16x8*)(ob + (long)r*NP + 8) = hi;
  }
  // xt2
  if (m0 < NN){
    unsigned short* o2 = xt2 + ((long)b*NN + m0) * TCN;
    int rows = (NN - m0 < 16) ? (NN - m0) : 16;
    for (int i = threadIdx.x; i < rows*TCN; i += 256){
      int mi = i / TCN, r = i - mi*TCN;
      int t = r >> 5, c = r & 31;
      o2[i] = tile[mi*768 + c*24 + t];
    }
  }
}

// ---------------- K0c: weights -> f-major bf16 ------------------------------------------
__global__ void k0_w(const float* __restrict__ Theta, const float* __restrict__ tw,
                     const float* __restrict__ rw,
                     unsigned short* __restrict__ ThT, unsigned short* __restrict__ WtT,
                     unsigned short* __restrict__ rwT){
  int i = blockIdx.x * 256 + threadIdx.x;
  if (i < 64*96){                       // ThT[f][kc] = Theta[k][c][f]
    int f = i / 96, kc = i - f*96;
    ThT[i] = f2bf(Theta[kc*64 + f]);
  }
  if (i < 64*192){                      // WtT[f][dt*64+fi] = tw[f][fi][0][dt]
    int f = i / 192, kk = i - f*192;
    int dt = kk >> 6, fi = kk & 63;
    WtT[i] = f2bf(tw[(f*64 + fi)*3 + dt]);
  }
  if (i < 64*32){                       // rwT[f][c] = rw[f][c][0][0]
    rwT[i] = f2bf(rw[i]);
  }
}

// ---------------- K1: fused cheb-GEMM (3k) + Theta-GEMM + relu -> spatial ----------------
// grid: ((b*8 + nt)*6 + tct), 512 threads (8 waves: 4 n-rows x 2 tc-cols)
__global__ __launch_bounds__(512, 2) void k1_cheb_theta(
    const unsigned short* __restrict__ cbT,
    const unsigned short* __restrict__ xbT,
    const unsigned short* __restrict__ ThT,
    unsigned short* __restrict__ spa)
{
  __shared__ unsigned short smem[26624];   // 53248 B: staging (20480 el) / y_l (26624 el)
  unsigned short* Al = smem;               // [3][128][40]
  unsigned short* Bl = smem + 3*128*40;    // [128][40]

  int bidx = blockIdx.x;
  const int tct = bidx % 6; bidx /= 6;
  const int nt  = bidx & 7;
  const int b   = bidx >> 3;

  const int tid  = threadIdx.x;
  const int wid  = tid >> 6;
  const int lane = tid & 63;
  const int l16  = lane & 15;
  const int k8   = lane >> 4;
  const int wr   = wid >> 1;   // 0..3 -> 32 n rows each
  const int wc   = wid & 1;    // 0..1 -> 64 tc cols each

  const int srow = tid >> 2;          // 0..127
  const int scol = (tid & 3) << 3;    // 0,8,16,24
  const unsigned short* gA0 = cbT + (nt*128 + srow)*NP + scol;
  const unsigned short* gB  = xbT + ((long)b*TCN + tct*128 + srow)*NP + scol;
  unsigned short* lA = Al + srow*40 + scol;
  unsigned short* lB = Bl + srow*40 + scol;

  f32x4 acc[3][2][4];
  #pragma unroll
  for (int k = 0; k < 3; ++k)
    #pragma unroll
    for (int i = 0; i < 2; ++i)
      #pragma unroll
      for (int j = 0; j < 4; ++j) acc[k][i][j] = (f32x4){0.f, 0.f, 0.f, 0.f};

  u16x8 rA0, rA1, rA2, rB;
  rA0 = *(const u16x8*)(gA0);
  rA1 = *(const u16x8*)(gA0 + NP*NP);
  rA2 = *(const u16x8*)(gA0 + 2*NP*NP);
  rB  = *(const u16x8*)(gB);

  for (int step = 0; step < 32; ++step){
    __syncthreads();
    *(u16x8*)(lA)          = rA0;
    *(u16x8*)(lA + 5120)   = rA1;
    *(u16x8*)(lA + 10240)  = rA2;
    *(u16x8*)(lB)          = rB;
    __syncthreads();
    if (step < 31){
      const int mo = (step + 1) * 32;
      rA0 = *(const u16x8*)(gA0 + mo);
      rA1 = *(const u16x8*)(gA0 + NP*NP + mo);
      rA2 = *(const u16x8*)(gA0 + 2*NP*NP + mo);
      rB  = *(const u16x8*)(gB + mo);
    }
    s16x8 af[3][2], bf[4];
    #pragma unroll
    for (int k = 0; k < 3; ++k)
      #pragma unroll
      for (int i = 0; i < 2; ++i)
        af[k][i] = *(const s16x8*)(Al + k*5120 + (wr*32 + i*16 + l16)*40 + k8*8);
    #pragma unroll
    for (int j = 0; j < 4; ++j)
      bf[j] = *(const s16x8*)(Bl + (wc*64 + j*16 + l16)*40 + k8*8);
    #pragma unroll
    for (int k = 0; k < 3; ++k)
      #pragma unroll
      for (int i = 0; i < 2; ++i)
        #pragma unroll
        for (int j = 0; j < 4; ++j)
          acc[k][i][j] = __builtin_amdgcn_mfma_f32_16x16x32_bf16(af[k][i], bf[j], acc[k][i][j], 0, 0, 0);
  }

  // Theta B-fragments (global, L2-hot)
  s16x8 b2[3][4];
  #pragma unroll
  for (int ch = 0; ch < 3; ++ch)
    #pragma unroll
    for (int j = 0; j < 4; ++j)
      b2[ch][j] = *(const s16x8*)(ThT + (j*16 + l16)*96 + ch*32 + k8*8);

  unsigned short* yl = smem;   // [2 t][128 n][104 kc]
  #pragma unroll
  for (int p = 0; p < 2; ++p){
    __syncthreads();
    if (wc == p){
      #pragma unroll
      for (int k = 0; k < 3; ++k)
        #pragma unroll
        for (int i = 0; i < 2; ++i)
          #pragma unroll
          for (int j = 0; j < 4; ++j){
            const int tl = j >> 1;
            const int c  = ((j & 1) << 4) + l16;
            const int nb = wr*32 + i*16 + (k8 << 2);
            #pragma unroll
            for (int r = 0; r < 4; ++r)
              yl[(tl*128 + nb + r)*104 + k*32 + c] = f2bf(acc[k][i][j][r]);
          }
    }
    __syncthreads();
    f32x4 acc2[2][4];
    #pragma unroll
    for (int tl = 0; tl < 2; ++tl)
      #pragma unroll
      for (int j = 0; j < 4; ++j) acc2[tl][j] = (f32x4){0.f, 0.f, 0.f, 0.f};
    #pragma unroll
    for (int tl = 0; tl < 2; ++tl)
      #pragma unroll
      for (int ch = 0; ch < 3; ++ch){
        s16x8 a2 = *(const s16x8*)(yl + (tl*128 + wid*16 + l16)*104 + ch*32 + k8*8);
        #pragma unroll
        for (int j = 0; j < 4; ++j)
          acc2[tl][j] = __builtin_amdgcn_mfma_f32_16x16x32_bf16(a2, b2[ch][j], acc2[tl][j], 0, 0, 0);
      }
    #pragma unroll
    for (int tl = 0; tl < 2; ++tl)
      #pragma unroll
      for (int j = 0; j < 4; ++j)
        #pragma unroll
        for (int r = 0; r < 4; ++r){
          int n = nt*128 + wid*16 + (k8 << 2) + r;
          if (n < NN){
            int f  = j*16 + l16;
            int tg = tct*4 + p*2 + tl;
            spa[((b*NN + n)*NT + tg)*64 + f] = f2bf(fmaxf(acc2[tl][j][r], 0.f));
          }
        }
  }
}

// ---------------- K2: time-conv (K=192) + residual (K=32) + gating -> out f32 -----------
__global__ __launch_bounds__(256, 2) void k2_out(
    const unsigned short* __restrict__ spa, const unsigned short* __restrict__ xt2,
    const unsigned short* __restrict__ WtT, const unsigned short* __restrict__ rwT,
    const float* __restrict__ tb, const float* __restrict__ rb,
    float* __restrict__ out)
{
  const int tid  = threadIdx.x;
  const int wid  = tid >> 6;
  const int lane = tid & 63;
  const int l16  = lane & 15;
  const int k8   = lane >> 4;
  const int gwave = blockIdx.x * 4 + wid;     // 0..5999

  s16x8 bw[6][4], br[4];
  #pragma unroll
  for (int ch = 0; ch < 6; ++ch)
    #pragma unroll
    for (int j = 0; j < 4; ++j)
      bw[ch][j] = *(const s16x8*)(WtT + (j*16 + l16)*192 + ch*32 + k8*8);
  #pragma unroll
  for (int j = 0; j < 4; ++j)
    br[j] = *(const s16x8*)(rwT + (j*16 + l16)*32 + k8*8);
  float tbv[4], rbv[4];
  #pragma unroll
  for (int j = 0; j < 4; ++j){ tbv[j] = tb[j*16 + l16]; rbv[j] = rb[j*16 + l16]; }

  for (int it = 0; it < 8; ++it){
    const int r0 = (gwave*8 + it) * 16;       // base row, rows = (b*1000+n)*24+t
    const int rowA = r0 + l16;
    const int tA = rowA % 24;
    const int bn = rowA / 24;
    f32x4 acc_tc[4], acc_res[4];
    #pragma unroll
    for (int j = 0; j < 4; ++j){ acc_tc[j] = (f32x4){0.f,0.f,0.f,0.f}; acc_res[j] = (f32x4){0.f,0.f,0.f,0.f}; }

    #pragma unroll
    for (int ch = 0; ch < 6; ++ch){
      const int dt = ch >> 1, fh = (ch & 1) << 5;
      const int ts = tA + dt - 1;
      s16x8 a = (s16x8){0,0,0,0,0,0,0,0};
      if (ts >= 0 && ts < 24)
        a = *(const s16x8*)(spa + ((bn*24 + ts) << 6) + fh + k8*8);
      #pragma unroll
      for (int j = 0; j < 4; ++j)
        acc_tc[j] = __builtin_amdgcn_mfma_f32_16x16x32_bf16(a, bw[ch][j], acc_tc[j], 0, 0, 0);
    }
    {
      s16x8 a = *(const s16x8*)(xt2 + (long)bn*768 + tA*32 + k8*8);
      #pragma unroll
      for (int j = 0; j < 4; ++j)
        acc_res[j] = __builtin_amdgcn_mfma_f32_16x16x32_bf16(a, br[j], acc_res[j], 0, 0, 0);
    }

    const int rowD = r0 + (k8 << 2);
    const int tD  = rowD % 24;                // multiple of 4, +3 never crosses 24
    const int bnD = rowD / 24;
    #pragma unroll
    for (int j = 0; j < 4; ++j){
      f32x4 v;
      #pragma unroll
      for (int r = 0; r < 4; ++r){
        float z  = acc_tc[j][r] + tbv[j];
        float s  = 1.f / (1.f + __expf(-z));
        float th = 2.f / (1.f + __expf(-2.f*z)) - 1.f;
        v[r] = acc_res[j][r] + rbv[j] + th * s;
      }
      *(f32x4*)(out + ((bnD << 6) + j*16 + l16)*24 + tD) = v;
    }
  }
}

// ---------------- launch -----------------------------------------------------------------
extern "C" void kernel_launch(void* const* d_in, const int* in_sizes, int n_in,
                              void* d_out, int out_size, void* d_ws, size_t ws_size,
                              hipStream_t stream) {
  const float* x     = (const float*)d_in[0];
  const float* cheb  = (const float*)d_in[1];
  const float* Theta = (const float*)d_in[2];
  const float* tw    = (const float*)d_in[3];
  const float* tb    = (const float*)d_in[4];
  const float* rw    = (const float*)d_in[5];
  const float* rb    = (const float*)d_in[6];
  float* out = (float*)d_out;

  char* ws = (char*)d_ws;
  size_t off = 0;
  auto alloc = [&](size_t bytes) -> void* {
    void* p = ws + off;
    off += (bytes + 255) & ~(size_t)255;
    return p;
  };
  unsigned short* cbT = (unsigned short*)alloc((size_t)3*NP*NP*2);        //  6.3 MB
  unsigned short* xbT = (unsigned short*)alloc((size_t)NB*TCN*NP*2);      // 50.3 MB
  unsigned short* xt2 = (unsigned short*)alloc((size_t)NB*NN*TCN*2);      // 49.2 MB
  unsigned short* spa = (unsigned short*)alloc((size_t)NB*NN*NT*64*2);    // 98.3 MB
  unsigned short* ThT = (unsigned short*)alloc((size_t)64*96*2);
  unsigned short* WtT = (unsigned short*)alloc((size_t)64*192*2);
  unsigned short* rwT = (unsigned short*)alloc((size_t)64*32*2);

  hipLaunchKernelGGL(k0_cheb, dim3(3072), dim3(256), 0, stream, cheb, cbT);
  hipLaunchKernelGGL(k0_x,    dim3(2048), dim3(256), 0, stream, x, xbT, xt2);
  hipLaunchKernelGGL(k0_w,    dim3(48),   dim3(256), 0, stream, Theta, tw, rw, ThT, WtT, rwT);
  hipLaunchKernelGGL(k1_cheb_theta, dim3(32*8*6), dim3(512), 0, stream, cbT, xbT, ThT, spa);
  hipLaunchKernelGGL(k2_out,  dim3(1500), dim3(256), 0, stream, spa, xt2, WtT, rwT, tb, rb, out);
}

// Round 2
// 443.871 us; speedup vs baseline: 1.1321x; 1.1321x over previous
//
#include <hip/hip_runtime.h>
#include <math.h>

typedef __attribute__((ext_vector_type(4))) float f32x4;
typedef __attribute__((ext_vector_type(8))) short s16x8;
typedef __attribute__((ext_vector_type(8))) unsigned short u16x8;
typedef __attribute__((ext_vector_type(4))) unsigned short u16x4;

#define NB 32
#define NN 1000
#define NT 24
#define NP 1024
#define TCN 768

#define GLOAD16(g, l) __builtin_amdgcn_global_load_lds( \
    (const __attribute__((address_space(1))) unsigned int*)(g), \
    (__attribute__((address_space(3))) unsigned int*)(l), 16, 0, 0)

__device__ __forceinline__ unsigned short f2bf(float f){
  union { float fv; unsigned int u; } v; v.fv = f;
  unsigned int r = v.u + 0x7FFFu + ((v.u >> 16) & 1u);
  return (unsigned short)(r >> 16);
}

// ---------------- K0a: cheb[3][1000][1000] f32 -> cbT[3][1024][1024] bf16 (zero pad) ----
__global__ void k0_cheb(const float* __restrict__ cheb, unsigned short* __restrict__ cbT){
  int idx = blockIdx.x * 256 + threadIdx.x;      // 3*1024*1024/4 threads
  int base = idx << 2;
  int m = base & (NP - 1);
  int r = base >> 10;
  int n = r & (NP - 1);
  int k = r >> 10;
  u16x4 o;
  #pragma unroll
  for (int i = 0; i < 4; ++i){
    int mm = m + i;
    float v = (n < NN && mm < NN) ? cheb[((long)k*NN + n)*NN + mm] : 0.f;
    o[i] = f2bf(v);
  }
  *(u16x4*)(cbT + base) = o;
}

// ---------------- K0b: x[b][m][c][t] f32 -> xbT[b][t*32+c][1024 m] bf16 (pad m)
//                                        -> xt2[b][m][t*32+c] bf16 -----------------------
// 64 m-rows per block: xbT row writes become 128B-contiguous segments.
__global__ __launch_bounds__(256) void k0_x(const float* __restrict__ x,
                     unsigned short* __restrict__ xbT, unsigned short* __restrict__ xt2){
  __shared__ unsigned short tile[64*770];        // pad 770: transpose reads conflict-free
  const int b  = blockIdx.x >> 4;
  const int m0 = (blockIdx.x & 15) << 6;
  const int tid = threadIdx.x;
  for (int i = tid; i < 64*192; i += 256){
    int mi = i / 192, c4 = (i - mi*192) << 2;
    f32x4 v = (f32x4){0.f,0.f,0.f,0.f};
    if (m0 + mi < NN) v = *(const f32x4*)(x + (size_t)(b*NN + m0 + mi)*768 + c4);
    unsigned short* tp = tile + mi*770 + c4;
    tp[0] = f2bf(v[0]); tp[1] = f2bf(v[1]); tp[2] = f2bf(v[2]); tp[3] = f2bf(v[3]);
  }
  __syncthreads();
  {
    const int seg = tid & 7, r0 = tid >> 3;
    for (int rr = 0; rr < 768; rr += 32){
      int r = rr + r0;
      int t = r >> 5, c = r & 31, ct = c*24 + t;
      u16x8 v;
      #pragma unroll
      for (int e = 0; e < 8; ++e) v[e] = tile[(seg*8 + e)*770 + ct];
      *(u16x8*)(xbT + ((size_t)b*TCN + r)*NP + m0 + seg*8) = v;
    }
  }
  if (m0 < NN){
    int rows = NN - m0; if (rows > 64) rows = 64;
    for (int i = tid; i < rows*96; i += 256){
      int mi = i / 96, s = i - mi*96;
      u16x8 v;
      #pragma unroll
      for (int e = 0; e < 8; ++e){
        int r = s*8 + e; int t = r >> 5, c = r & 31;
        v[e] = tile[mi*770 + c*24 + t];
      }
      *(u16x8*)(xt2 + (size_t)(b*NN + m0 + mi)*TCN + s*8) = v;
    }
  }
}

// ---------------- K0c: weights -> f-major bf16 ------------------------------------------
__global__ void k0_w(const float* __restrict__ Theta, const float* __restrict__ tw,
                     const float* __restrict__ rw,
                     unsigned short* __restrict__ ThT, unsigned short* __restrict__ WtT,
                     unsigned short* __restrict__ rwT){
  int i = blockIdx.x * 256 + threadIdx.x;
  if (i < 64*96){                       // ThT[f][kc] = Theta[k][c][f]
    int f = i / 96, kc = i - f*96;
    ThT[i] = f2bf(Theta[kc*64 + f]);
  }
  if (i < 64*192){                      // WtT[f][dt*64+fi] = tw[f][fi][0][dt]
    int f = i / 192, kk = i - f*192;
    int dt = kk >> 6, fi = kk & 63;
    WtT[i] = f2bf(tw[(f*64 + fi)*3 + dt]);
  }
  if (i < 64*32){                       // rwT[f][c] = rw[f][c][0][0]
    rwT[i] = f2bf(rw[i]);
  }
}

// ---------------- K1: fused cheb-GEMM (3k) + Theta-GEMM + relu -> spatial ----------------
// 256 threads (4 waves), block tile 128n x 64tc x 3k, BK=64, global_load_lds staging
// with both-sides XOR chunk swizzle (chunk^(row&7)); 16 K-steps.
__global__ __launch_bounds__(256, 2) void k1_cheb_theta(
    const unsigned short* __restrict__ cbT,
    const unsigned short* __restrict__ xbT,
    const unsigned short* __restrict__ ThT,
    unsigned short* __restrict__ spa)
{
  __shared__ __align__(16) unsigned short smem[28672];  // 57.3KB: A[3][128][64]+B[64][64]; yl [2][128][104]

  int p = blockIdx.x;
  int lb = (p & 7) * 384 + (p >> 3);       // bijective XCD-chunked swizzle (3072 = 8*384)
  const int tct = lb % 12; lb /= 12;       // inner: 12 consecutive blocks share A-panel
  const int nt  = lb & 7;
  const int b   = lb >> 3;

  const int tid  = threadIdx.x;
  const int wid  = tid >> 6;      // 0..3 : n rows wid*32..wid*32+31
  const int lane = tid & 63;
  const int l16  = lane & 15;
  const int k8   = lane >> 4;

  // staging lane constants (per-lane swizzled global source, linear LDS dest)
  const int rl  = lane >> 3;                    // row within 8-row group
  const int cg8 = (((lane & 7) ^ rl) << 3);     // swizzled source chunk * 8 elems

  const unsigned short* gA = cbT + (size_t)(nt*128 + rl) * NP + cg8;
  const unsigned short* gB = xbT + ((size_t)b*TCN + tct*64 + rl) * NP + cg8;

  f32x4 acc[3][2][4];
  #pragma unroll
  for (int k = 0; k < 3; ++k)
    #pragma unroll
    for (int i = 0; i < 2; ++i)
      #pragma unroll
      for (int j = 0; j < 4; ++j) acc[k][i][j] = (f32x4){0.f, 0.f, 0.f, 0.f};

  for (int step = 0; step < 16; ++step){
    __syncthreads();                           // previous step's reads done
    const int so = step * 64;
    #pragma unroll
    for (int q = 0; q < 14; ++q){
      const int g = wid * 14 + q;              // 56 1KB loads: 48 A + 8 B
      if (g < 48){
        const int k = g >> 4, row8 = g & 15;
        GLOAD16(gA + (size_t)k*NP*NP + (size_t)row8*8*NP + so,
                (char*)smem + k*16384 + row8*1024);
      } else {
        const int row8 = g - 48;
        GLOAD16(gB + (size_t)row8*8*NP + so,
                (char*)smem + 49152 + row8*1024);
      }
    }
    __syncthreads();                           // drains vmcnt -> data visible
    #pragma unroll
    for (int ks = 0; ks < 2; ++ks){
      const int ph = (((ks << 2) + k8) ^ (l16 & 7)) << 3;  // swizzled read chunk offset
      s16x8 af[3][2], bf[4];
      #pragma unroll
      for (int k = 0; k < 3; ++k)
        #pragma unroll
        for (int i = 0; i < 2; ++i){
          const int ra = wid*32 + i*16 + l16;
          af[k][i] = *(const s16x8*)(smem + k*8192 + ra*64 + ph);
        }
      #pragma unroll
      for (int j = 0; j < 4; ++j){
        const int rb = j*16 + l16;
        bf[j] = *(const s16x8*)(smem + 24576 + rb*64 + ph);
      }
      #pragma unroll
      for (int k = 0; k < 3; ++k)
        #pragma unroll
        for (int i = 0; i < 2; ++i)
          #pragma unroll
          for (int j = 0; j < 4; ++j)
            acc[k][i][j] = __builtin_amdgcn_mfma_f32_16x16x32_bf16(af[k][i], bf[j], acc[k][i][j], 0, 0, 0);
    }
  }

  // ---- epilogue: y -> LDS (bf16) -> Theta MFMA -> relu -> spa ----
  __syncthreads();
  unsigned short* yl = smem;                   // [2 t][128 n][104 kc]
  #pragma unroll
  for (int k = 0; k < 3; ++k)
    #pragma unroll
    for (int i = 0; i < 2; ++i)
      #pragma unroll
      for (int j = 0; j < 4; ++j){
        const int t = j >> 1;
        const int c = ((j & 1) << 4) + l16;
        const int nb = wid*32 + i*16 + (k8 << 2);
        #pragma unroll
        for (int r = 0; r < 4; ++r)
          yl[(t*128 + nb + r)*104 + k*32 + c] = f2bf(acc[k][i][j][r]);
      }
  __syncthreads();

  s16x8 b2[3][4];
  #pragma unroll
  for (int ch = 0; ch < 3; ++ch)
    #pragma unroll
    for (int j = 0; j < 4; ++j)
      b2[ch][j] = *(const s16x8*)(ThT + (j*16 + l16)*96 + ch*32 + k8*8);

  f32x4 acc2[2][2][4];
  #pragma unroll
  for (int t = 0; t < 2; ++t)
    #pragma unroll
    for (int i = 0; i < 2; ++i)
      #pragma unroll
      for (int j = 0; j < 4; ++j) acc2[t][i][j] = (f32x4){0.f,0.f,0.f,0.f};

  #pragma unroll
  for (int t = 0; t < 2; ++t)
    #pragma unroll
    for (int i = 0; i < 2; ++i)
      #pragma unroll
      for (int ch = 0; ch < 3; ++ch){
        s16x8 a2 = *(const s16x8*)(yl + (size_t)(t*128 + wid*32 + i*16 + l16)*104 + ch*32 + k8*8);
        #pragma unroll
        for (int j = 0; j < 4; ++j)
          acc2[t][i][j] = __builtin_amdgcn_mfma_f32_16x16x32_bf16(a2, b2[ch][j], acc2[t][i][j], 0, 0, 0);
      }

  #pragma unroll
  for (int t = 0; t < 2; ++t)
    #pragma unroll
    for (int i = 0; i < 2; ++i)
      #pragma unroll
      for (int j = 0; j < 4; ++j)
        #pragma unroll
        for (int r = 0; r < 4; ++r){
          const int n = nt*128 + wid*32 + i*16 + (k8 << 2) + r;
          if (n < NN){
            const int f  = j*16 + l16;
            const int tg = tct*2 + t;
            spa[((size_t)(b*NN + n)*NT + tg)*64 + f] = f2bf(fmaxf(acc2[t][i][j][r], 0.f));
          }
        }
}

// ---------------- K2: time-conv (K=192) + residual (K=32) + gating -> out f32 -----------
__global__ __launch_bounds__(256, 2) void k2_out(
    const unsigned short* __restrict__ spa, const unsigned short* __restrict__ xt2,
    const unsigned short* __restrict__ WtT, const unsigned short* __restrict__ rwT,
    const float* __restrict__ tb, const float* __restrict__ rb,
    float* __restrict__ out)
{
  const int tid  = threadIdx.x;
  const int wid  = tid >> 6;
  const int lane = tid & 63;
  const int l16  = lane & 15;
  const int k8   = lane >> 4;
  const int gwave = blockIdx.x * 4 + wid;     // 0..5999

  s16x8 bw[6][4], br[4];
  #pragma unroll
  for (int ch = 0; ch < 6; ++ch)
    #pragma unroll
    for (int j = 0; j < 4; ++j)
      bw[ch][j] = *(const s16x8*)(WtT + (j*16 + l16)*192 + ch*32 + k8*8);
  #pragma unroll
  for (int j = 0; j < 4; ++j)
    br[j] = *(const s16x8*)(rwT + (j*16 + l16)*32 + k8*8);
  float tbv[4], rbv[4];
  #pragma unroll
  for (int j = 0; j < 4; ++j){ tbv[j] = tb[j*16 + l16]; rbv[j] = rb[j*16 + l16]; }

  for (int it = 0; it < 8; ++it){
    const int r0 = (gwave*8 + it) * 16;       // base row, rows = (b*1000+n)*24+t
    const int rowA = r0 + l16;
    const int tA = rowA % 24;
    const int bn = rowA / 24;
    f32x4 acc_tc[4], acc_res[4];
    #pragma unroll
    for (int j = 0; j < 4; ++j){ acc_tc[j] = (f32x4){0.f,0.f,0.f,0.f}; acc_res[j] = (f32x4){0.f,0.f,0.f,0.f}; }

    #pragma unroll
    for (int ch = 0; ch < 6; ++ch){
      const int dt = ch >> 1, fh = (ch & 1) << 5;
      const int ts = tA + dt - 1;
      s16x8 a = (s16x8){0,0,0,0,0,0,0,0};
      if (ts >= 0 && ts < 24)
        a = *(const s16x8*)(spa + ((size_t)(bn*24 + ts) << 6) + fh + k8*8);
      #pragma unroll
      for (int j = 0; j < 4; ++j)
        acc_tc[j] = __builtin_amdgcn_mfma_f32_16x16x32_bf16(a, bw[ch][j], acc_tc[j], 0, 0, 0);
    }
    {
      s16x8 a = *(const s16x8*)(xt2 + (size_t)bn*768 + tA*32 + k8*8);
      #pragma unroll
      for (int j = 0; j < 4; ++j)
        acc_res[j] = __builtin_amdgcn_mfma_f32_16x16x32_bf16(a, br[j], acc_res[j], 0, 0, 0);
    }

    const int rowD = r0 + (k8 << 2);
    const int tD  = rowD % 24;                // multiple of 4, +3 never crosses 24
    const int bnD = rowD / 24;
    #pragma unroll
    for (int j = 0; j < 4; ++j){
      f32x4 v;
      #pragma unroll
      for (int r = 0; r < 4; ++r){
        float z  = acc_tc[j][r] + tbv[j];
        float s  = 1.f / (1.f + __expf(-z));
        float th = 2.f / (1.f + __expf(-2.f*z)) - 1.f;
        v[r] = acc_res[j][r] + rbv[j] + th * s;
      }
      *(f32x4*)(out + (((size_t)bnD << 6) + j*16 + l16)*24 + tD) = v;
    }
  }
}

// ---------------- launch -----------------------------------------------------------------
extern "C" void kernel_launch(void* const* d_in, const int* in_sizes, int n_in,
                              void* d_out, int out_size, void* d_ws, size_t ws_size,
                              hipStream_t stream) {
  const float* x     = (const float*)d_in[0];
  const float* cheb  = (const float*)d_in[1];
  const float* Theta = (const float*)d_in[2];
  const float* tw    = (const float*)d_in[3];
  const float* tb    = (const float*)d_in[4];
  const float* rw    = (const float*)d_in[5];
  const float* rb    = (const float*)d_in[6];
  float* out = (float*)d_out;

  char* ws = (char*)d_ws;
  size_t off = 0;
  auto alloc = [&](size_t bytes) -> void* {
    void* p = ws + off;
    off += (bytes + 255) & ~(size_t)255;
    return p;
  };
  unsigned short* cbT = (unsigned short*)alloc((size_t)3*NP*NP*2);        //  6.3 MB
  unsigned short* xbT = (unsigned short*)alloc((size_t)NB*TCN*NP*2);      // 50.3 MB
  unsigned short* xt2 = (unsigned short*)alloc((size_t)NB*NN*TCN*2);      // 49.2 MB
  unsigned short* spa = (unsigned short*)alloc((size_t)NB*NN*NT*64*2);    // 98.3 MB
  unsigned short* ThT = (unsigned short*)alloc((size_t)64*96*2);
  unsigned short* WtT = (unsigned short*)alloc((size_t)64*192*2);
  unsigned short* rwT = (unsigned short*)alloc((size_t)64*32*2);

  hipLaunchKernelGGL(k0_cheb, dim3(3072), dim3(256), 0, stream, cheb, cbT);
  hipLaunchKernelGGL(k0_x,    dim3(512),  dim3(256), 0, stream, x, xbT, xt2);
  hipLaunchKernelGGL(k0_w,    dim3(48),   dim3(256), 0, stream, Theta, tw, rw, ThT, WtT, rwT);
  hipLaunchKernelGGL(k1_cheb_theta, dim3(32*8*12), dim3(256), 0, stream, cbT, xbT, ThT, spa);
  hipLaunchKernelGGL(k2_out,  dim3(1500), dim3(256), 0, stream, spa, xt2, WtT, rwT, tb, rb, out);
}